// Round 8
// baseline (905.000 us; speedup 1.0000x reference)
//
#include <hip/hip_runtime.h>
#include <math.h>

// Problem constants
constexpr int kN  = 50000;     // nodes
constexpr int kE  = 600000;    // raw edges
constexpr int kET = 650000;    // edges + self loops
constexpr int kG  = 50;        // graphs
constexpr int kH  = 4;         // heads

// ws layout (float-slot offsets)
constexpr size_t OFF_HCUR   = 0;           // N*64 bf16  -> 1.6M float slots
constexpr size_t OFF_HNEXT  = 1600000;     // N*64 f32   -> 3.2M
constexpr size_t OFF_Z      = 4800000;     // N*256 bf16 -> 6.4M slots
constexpr size_t OFF_ES     = 11200000;    // N*4 f32
constexpr size_t OFF_ED     = 11400000;    // N*4 f32
constexpr size_t OFF_ROWPTR = 14200000;    // (N+1) ints
constexpr size_t OFF_CURSOR = 14260000;    // N ints
constexpr size_t OFF_SRC    = 14320000;    // ET ints
constexpr size_t OFF_WT2    = 14970000;    // 3 layers x 16384 bf16
constexpr size_t OFF_AHAT   = 15000000;    // 3 layers x 512 f32
constexpr size_t OFF_BN     = 15002000;    // 128 f32 (sum[0:D], sumsq[D:2D])
constexpr size_t OFF_GPOOL  = 15003000;    // gsum[1600] f32 + gmaxe[1600] u32
constexpr size_t OFF_SPART  = 15008000;    // 64 ints (scan partials)
constexpr size_t OFF_PART2  = 15010000;    // zgemm stats partials (<=1563*128 f32)

constexpr int kScanBlocks = (kN + 1023) / 1024;  // 49

typedef __bf16 bf16x8 __attribute__((ext_vector_type(8)));
typedef float  f32x4  __attribute__((ext_vector_type(4)));

__device__ inline ushort f2b(float f) {  // RNE float->bf16 bits
    unsigned u = __float_as_uint(f);
    return (ushort)((u + 0x7FFFu + ((u >> 16) & 1u)) >> 16);
}
__device__ inline float b2f(ushort u) {
    return __uint_as_float(((unsigned)u) << 16);
}
__device__ inline unsigned enc_f(float f) {  // monotone float->uint
    unsigned b = __float_as_uint(f);
    return (b & 0x80000000u) ? ~b : (b | 0x80000000u);
}
__device__ inline float dec_f(unsigned u) {
    return __uint_as_float((u & 0x80000000u) ? (u & 0x7FFFFFFFu) : ~u);
}

__device__ inline void edge_pair(const int* __restrict__ ei, int e, int& src, int& dst) {
    if (e < kE) { src = ei[e]; dst = ei[kE + e]; }
    else        { src = e - kE; dst = e - kE; }
}

// ---------------- CSR build (once per launch) ----------------
__global__ void k_hist(const int* __restrict__ ei, int* __restrict__ counts) {
    int e = blockIdx.x * blockDim.x + threadIdx.x;
    if (e >= kET) return;
    int src, dst;
    edge_pair(ei, e, src, dst);
    atomicAdd(&counts[dst], 1);
}

__global__ void __launch_bounds__(1024) k_scan_local(const int* __restrict__ counts,
                                                     int* __restrict__ rowptr,
                                                     int* __restrict__ partials) {
    int tid = threadIdx.x;
    int idx = blockIdx.x * 1024 + tid;
    int val = (idx < kN) ? counts[idx] : 0;
    int lane = tid & 63, w = tid >> 6;
    int x = val;
#pragma unroll
    for (int off = 1; off < 64; off <<= 1) {
        int t = __shfl_up(x, off);
        if (lane >= off) x += t;
    }
    __shared__ int wsum[16];
    if (lane == 63) wsum[w] = x;
    __syncthreads();
    if (w == 0 && lane < 16) {
        int y = wsum[lane];
#pragma unroll
        for (int off = 1; off < 16; off <<= 1) {
            int t = __shfl_up(y, off);
            if (lane >= off) y += t;
        }
        wsum[lane] = y;
    }
    __syncthreads();
    int incl = x + (w > 0 ? wsum[w - 1] : 0);
    if (idx < kN) rowptr[idx + 1] = incl;
    if (tid == 1023) partials[blockIdx.x] = incl;
}

__global__ void k_scan_part(int* __restrict__ partials) {
    int lane = threadIdx.x;
    int v = (lane < kScanBlocks) ? partials[lane] : 0;
    int x = v;
#pragma unroll
    for (int off = 1; off < 64; off <<= 1) {
        int t = __shfl_up(x, off);
        if (lane >= off) x += t;
    }
    if (lane < kScanBlocks) partials[lane] = x - v;
}

__global__ void __launch_bounds__(1024) k_scan_add(int* __restrict__ cursor,
                                                   int* __restrict__ rowptr,
                                                   const int* __restrict__ partials) {
    int idx = blockIdx.x * 1024 + threadIdx.x;
    if (idx >= kN) return;
    int incl = rowptr[idx + 1] + partials[blockIdx.x];
    rowptr[idx + 1] = incl;
    int val = cursor[idx];
    cursor[idx] = incl - val;
    if (idx == 0) rowptr[0] = 0;
}

__global__ void k_scatter(const int* __restrict__ ei, int* __restrict__ cursor,
                          int* __restrict__ src_csr) {
    int e = blockIdx.x * blockDim.x + threadIdx.x;
    if (e >= kET) return;
    int src, dst;
    edge_pair(ei, e, src, dst);
    int pos = atomicAdd(&cursor[dst], 1);
    src_csr[pos] = src;
}

// ---------------- weight prep: all 3 layers in one dispatch ----------------
__global__ void k_prep_all(const float* __restrict__ w0, const float* __restrict__ w1,
                           const float* __restrict__ w2, const float* __restrict__ as0,
                           const float* __restrict__ as1, const float* __restrict__ as2,
                           const float* __restrict__ ad0, const float* __restrict__ ad1,
                           const float* __restrict__ ad2, float* __restrict__ ahat,
                           ushort* __restrict__ Wt2) {
    int b = blockIdx.x;
    if (b < 3) {
        const float* W  = (b == 0) ? w0 : (b == 1) ? w1 : w2;
        const float* As = (b == 0) ? as0 : (b == 1) ? as1 : as2;
        const float* Ad = (b == 0) ? ad0 : (b == 1) ? ad1 : ad2;
        int dout = (b == 2) ? 32 : 64;
        int i = threadIdx.x;
        int h = i >> 6, k = i & 63;
        const float* wr = W + (size_t)k * (4 * dout) + h * dout;
        float s1 = 0.f, s2 = 0.f;
        for (int c = 0; c < dout; ++c) {
            float w = wr[c];
            s1 += w * As[h * dout + c];
            s2 += w * Ad[h * dout + c];
        }
        ahat[b * 512 + i] = s1;
        ahat[b * 512 + 256 + i] = s2;
    } else {
        int i = (b - 3) * 256 + threadIdx.x;   // over 40960
        if (i >= 40960) return;
        int l, li;
        if (i < 16384)      { l = 0; li = i; }
        else if (i < 32768) { l = 1; li = i - 16384; }
        else                { l = 2; li = i - 32768; }
        int dout = (l == 2) ? 32 : 64;
        const float* W = (l == 0) ? w0 : (l == 1) ? w1 : w2;
        int c = li >> 8, kk = li & 255;
        int h = kk >> 6, k = kk & 63;
        Wt2[l * 16384 + li] = f2b(W[(size_t)k * (4 * dout) + h * dout + c]);
    }
}

// ---------------- encoder + fused layer-0 es/ed ----------------
__global__ void __launch_bounds__(256) k_encoder_att(const float* __restrict__ x,
                                                     const float* __restrict__ w,
                                                     const float* __restrict__ b,
                                                     const float* __restrict__ ahat0,
                                                     ushort* __restrict__ h,
                                                     float* __restrict__ es,
                                                     float* __restrict__ ed) {
    int node = blockIdx.x * 4 + (threadIdx.x >> 6);
    int lane = threadIdx.x & 63;
    float acc = b[lane];
#pragma unroll
    for (int k = 0; k < 5; ++k) acc += x[node * 5 + k] * w[k * 64 + lane];
    h[(size_t)node * 64 + lane] = f2b(acc);

    float ps[4], pd[4];
#pragma unroll
    for (int hh = 0; hh < 4; ++hh) {
        ps[hh] = acc * ahat0[hh * 64 + lane];
        pd[hh] = acc * ahat0[256 + hh * 64 + lane];
    }
#pragma unroll
    for (int off = 1; off < 64; off <<= 1) {
#pragma unroll
        for (int hh = 0; hh < 4; ++hh) {
            ps[hh] += __shfl_xor(ps[hh], off);
            pd[hh] += __shfl_xor(pd[hh], off);
        }
    }
    if (lane == 0) {
        ((float4*)es)[node] = make_float4(ps[0], ps[1], ps[2], ps[3]);
        ((float4*)ed)[node] = make_float4(pd[0], pd[1], pd[2], pd[3]);
    }
}

// Fused edge-softmax + aggregation. One wave per dst.
__global__ void __launch_bounds__(256) k_gat(const int* __restrict__ rowptr,
                                             const int* __restrict__ srcc,
                                             const float* __restrict__ es,
                                             const float* __restrict__ ed,
                                             const ushort* __restrict__ h,
                                             ushort* __restrict__ z) {
    int wid = threadIdx.x >> 6;
    int lane = threadIdx.x & 63;
    int dst = blockIdx.x * 4 + wid;   // kN % 4 == 0
    int start = rowptr[dst], end = rowptr[dst + 1];
    int deg = end - start;

    int e_l = lane >> 2, hh = lane & 3;    // score mapping
    int q = lane >> 4, c4 = lane & 15;     // gather mapping

    float edv = ed[dst * 4 + hh];
    float acc[4][4] = {};
    float s;

    if (deg <= 16) {
        int pos = start + e_l;
        int psafe = (pos < end) ? pos : start;
        int src = srcc[psafe];
        float v = es[src * 4 + hh] + edv;
        v = (v >= 0.f) ? v : 0.2f * v;
        if (pos >= end) v = -3e38f;

        uint2 hv[4];
#pragma unroll
        for (int t = 0; t < 4; ++t) {
            int p2 = start + t * 4 + q;
            int p2s = (p2 < end) ? p2 : start;
            int s2 = srcc[p2s];
            hv[t] = *reinterpret_cast<const uint2*>(h + (size_t)s2 * 64 + c4 * 4);
        }

        float cm = v;
        cm = fmaxf(cm, __shfl_xor(cm, 4));
        cm = fmaxf(cm, __shfl_xor(cm, 8));
        cm = fmaxf(cm, __shfl_xor(cm, 16));
        cm = fmaxf(cm, __shfl_xor(cm, 32));
        float p = __expf(v - cm);
        float cs = p;
        cs += __shfl_xor(cs, 4);
        cs += __shfl_xor(cs, 8);
        cs += __shfl_xor(cs, 16);
        cs += __shfl_xor(cs, 32);
        s = cs;

#pragma unroll
        for (int t = 0; t < 4; ++t) {
            int el = t * 4 + q;
            float p0 = __shfl(p, (el << 2) | 0);
            float p1 = __shfl(p, (el << 2) | 1);
            float p2 = __shfl(p, (el << 2) | 2);
            float p3 = __shfl(p, (el << 2) | 3);
            float c0 = __uint_as_float(hv[t].x << 16);
            float c1 = __uint_as_float(hv[t].x & 0xFFFF0000u);
            float c2 = __uint_as_float(hv[t].y << 16);
            float c3 = __uint_as_float(hv[t].y & 0xFFFF0000u);
            acc[0][0] += p0 * c0; acc[0][1] += p0 * c1; acc[0][2] += p0 * c2; acc[0][3] += p0 * c3;
            acc[1][0] += p1 * c0; acc[1][1] += p1 * c1; acc[1][2] += p1 * c2; acc[1][3] += p1 * c3;
            acc[2][0] += p2 * c0; acc[2][1] += p2 * c1; acc[2][2] += p2 * c2; acc[2][3] += p2 * c3;
            acc[3][0] += p3 * c0; acc[3][1] += p3 * c1; acc[3][2] += p3 * c2; acc[3][3] += p3 * c3;
        }
    } else {
        float m = -3e38f;
        s = 0.f;
        for (int cs0 = start; cs0 < end; cs0 += 16) {
            int pos = cs0 + e_l;
            int psafe = (pos < end) ? pos : start;
            int src = srcc[psafe];
            float v = es[src * 4 + hh] + edv;
            v = (v >= 0.f) ? v : 0.2f * v;
            if (pos >= end) v = -3e38f;

            float cm = v;
            cm = fmaxf(cm, __shfl_xor(cm, 4));
            cm = fmaxf(cm, __shfl_xor(cm, 8));
            cm = fmaxf(cm, __shfl_xor(cm, 16));
            cm = fmaxf(cm, __shfl_xor(cm, 32));
            float mn = fmaxf(m, cm);
            float scale = __expf(m - mn);
            float p = __expf(v - mn);
            float cth = p;
            cth += __shfl_xor(cth, 4);
            cth += __shfl_xor(cth, 8);
            cth += __shfl_xor(cth, 16);
            cth += __shfl_xor(cth, 32);
            s = s * scale + cth;
            m = mn;

            float sc0 = __shfl(scale, 0), sc1 = __shfl(scale, 1);
            float sc2 = __shfl(scale, 2), sc3 = __shfl(scale, 3);
#pragma unroll
            for (int c = 0; c < 4; ++c) {
                acc[0][c] *= sc0; acc[1][c] *= sc1; acc[2][c] *= sc2; acc[3][c] *= sc3;
            }
#pragma unroll
            for (int t = 0; t < 4; ++t) {
                int el = t * 4 + q;
                int p2 = cs0 + el;
                int p2s = (p2 < end) ? p2 : start;
                int s2 = srcc[p2s];
                uint2 hv = *reinterpret_cast<const uint2*>(h + (size_t)s2 * 64 + c4 * 4);
                float p0 = __shfl(p, (el << 2) | 0);
                float p1 = __shfl(p, (el << 2) | 1);
                float p2f = __shfl(p, (el << 2) | 2);
                float p3 = __shfl(p, (el << 2) | 3);
                float c0 = __uint_as_float(hv.x << 16);
                float c1 = __uint_as_float(hv.x & 0xFFFF0000u);
                float c2 = __uint_as_float(hv.y << 16);
                float c3 = __uint_as_float(hv.y & 0xFFFF0000u);
                acc[0][0] += p0 * c0;  acc[0][1] += p0 * c1;  acc[0][2] += p0 * c2;  acc[0][3] += p0 * c3;
                acc[1][0] += p1 * c0;  acc[1][1] += p1 * c1;  acc[1][2] += p1 * c2;  acc[1][3] += p1 * c3;
                acc[2][0] += p2f * c0; acc[2][1] += p2f * c1; acc[2][2] += p2f * c2; acc[2][3] += p2f * c3;
                acc[3][0] += p3 * c0;  acc[3][1] += p3 * c1;  acc[3][2] += p3 * c2;  acc[3][3] += p3 * c3;
            }
        }
    }

    float myinv = 0.25f / (s + 1e-16f);
    float inv0 = __shfl(myinv, 0), inv1 = __shfl(myinv, 1);
    float inv2 = __shfl(myinv, 2), inv3 = __shfl(myinv, 3);
#pragma unroll
    for (int c = 0; c < 4; ++c) {
        acc[0][c] *= inv0; acc[1][c] *= inv1; acc[2][c] *= inv2; acc[3][c] *= inv3;
    }
#pragma unroll
    for (int j = 0; j < 4; ++j) {
#pragma unroll
        for (int c = 0; c < 4; ++c) {
            float v = acc[j][c];
            v += __shfl_xor(v, 16);
            v += __shfl_xor(v, 32);
            acc[j][c] = v;
        }
    }
    if (q == 0) {
        ushort* zr = z + (size_t)dst * 256 + c4 * 4;
#pragma unroll
        for (int j = 0; j < 4; ++j) {
            ushort4 o;
            o.x = f2b(acc[j][0]); o.y = f2b(acc[j][1]);
            o.z = f2b(acc[j][2]); o.w = f2b(acc[j][3]);
            *reinterpret_cast<ushort4*>(zr + j * 64) = o;
        }
    }
}

// MFMA GEMM with fused BN-stat partials. Wave = 16x32 tile, 16 MFMAs.
// Block writes one [2*DOUT] partial row (sum, sumsq) to part.
template <int DOUT>
__global__ void __launch_bounds__(256) k_zgemm(const ushort* __restrict__ z,
                                               const ushort* __restrict__ Wt2l,
                                               float* __restrict__ hnext,
                                               float* __restrict__ part) {
    constexpr int NG = DOUT / 32;
    constexpr int W = 2 * DOUT;
    __shared__ float pl[4][W];
    int tid = threadIdx.x;
    int widx = tid >> 6, lane = tid & 63;
    int wid = blockIdx.x * 4 + widx;
    int mtile = wid / NG;
    int ng = wid - mtile * NG;
    bool active = (mtile < kN / 16);
    int m0 = mtile * 16;
    int n0 = ng * 32;

    int row = lane & 15;
    int k0  = (lane >> 4) * 8;

    for (int j = tid; j < 4 * W; j += 256) (&pl[0][0])[j] = 0.f;

    f32x4 acc0 = {0.f, 0.f, 0.f, 0.f};
    f32x4 acc1 = {0.f, 0.f, 0.f, 0.f};
    if (active) {
        const ushort* za = z + (size_t)(m0 + row) * 256 + k0;
        bf16x8 a[8];
#pragma unroll
        for (int ks = 0; ks < 8; ++ks)
            a[ks] = *reinterpret_cast<const bf16x8*>(za + ks * 32);

        const ushort* wb0 = Wt2l + (size_t)(n0 + row) * 256 + k0;
        const ushort* wb1 = wb0 + 16 * 256;
#pragma unroll
        for (int ks = 0; ks < 8; ++ks) {
            bf16x8 b0 = *reinterpret_cast<const bf16x8*>(wb0 + ks * 32);
            bf16x8 b1 = *reinterpret_cast<const bf16x8*>(wb1 + ks * 32);
            acc0 = __builtin_amdgcn_mfma_f32_16x16x32_bf16(a[ks], b0, acc0, 0, 0, 0);
            acc1 = __builtin_amdgcn_mfma_f32_16x16x32_bf16(a[ks], b1, acc1, 0, 0, 0);
        }

        int col = lane & 15;
        int r0  = (lane >> 4) * 4;
#pragma unroll
        for (int r = 0; r < 4; ++r) {
            hnext[(size_t)(m0 + r0 + r) * DOUT + n0 + col]      = acc0[r];
            hnext[(size_t)(m0 + r0 + r) * DOUT + n0 + 16 + col] = acc1[r];
        }
    }

    // per-wave column stats (zeros if inactive)
    float s0 = 0.f, q0 = 0.f, s1 = 0.f, q1 = 0.f;
#pragma unroll
    for (int r = 0; r < 4; ++r) {
        s0 += acc0[r]; q0 += acc0[r] * acc0[r];
        s1 += acc1[r]; q1 += acc1[r] * acc1[r];
    }
    s0 += __shfl_xor(s0, 16); s0 += __shfl_xor(s0, 32);
    q0 += __shfl_xor(q0, 16); q0 += __shfl_xor(q0, 32);
    s1 += __shfl_xor(s1, 16); s1 += __shfl_xor(s1, 32);
    q1 += __shfl_xor(q1, 16); q1 += __shfl_xor(q1, 32);
    __syncthreads();
    if (lane < 16) {
        pl[widx][n0 + lane]            = s0;
        pl[widx][DOUT + n0 + lane]     = q0;
        pl[widx][n0 + 16 + lane]       = s1;
        pl[widx][DOUT + n0 + 16 + lane] = q1;
    }
    __syncthreads();
    if (tid < W) {
        float t = pl[0][tid] + pl[1][tid] + pl[2][tid] + pl[3][tid];
        part[(size_t)blockIdx.x * W + tid] = t;
    }
}

// reduce zgemm partials -> bn[0:2D)
template <int DOUT>
__global__ void k_bnred(const float* __restrict__ part, int nblocks,
                        float* __restrict__ bn) {
    constexpr int W = 2 * DOUT;
    constexpr int CH = 256 / W;
    __shared__ float red[256];
    int tid = threadIdx.x;
    int j = tid % W;
    int ch = tid / W;
    float s = 0.f;
    for (int b = ch; b < nblocks; b += CH) s += part[(size_t)b * W + j];
    red[tid] = s;
    __syncthreads();
    if (tid < W) {
        float t = red[tid];
#pragma unroll
        for (int c = 1; c < CH; ++c) t += red[c * W + tid];
        bn[tid] = t;
    }
}

// BN apply (layers 0,1) fused with NEXT layer's es/ed
__global__ void __launch_bounds__(256) k_bn_apply_att(const float* __restrict__ hnext,
                                                      const float* __restrict__ bn,
                                                      const float* __restrict__ g,
                                                      const float* __restrict__ be,
                                                      const float* __restrict__ ahat_next,
                                                      ushort* __restrict__ hcur,
                                                      float* __restrict__ es,
                                                      float* __restrict__ ed) {
    int node = blockIdx.x * 4 + (threadIdx.x >> 6);
    int lane = threadIdx.x & 63;
    float mu = bn[lane] * (1.f / kN);
    float var = bn[64 + lane] * (1.f / kN) - mu * mu;
    float v = g[lane] * (hnext[(size_t)node * 64 + lane] - mu) * rsqrtf(var + 1e-5f) + be[lane];
    v = fmaxf(v, 0.f);
    hcur[(size_t)node * 64 + lane] = f2b(v);

    float ps[4], pd[4];
#pragma unroll
    for (int hh = 0; hh < 4; ++hh) {
        ps[hh] = v * ahat_next[hh * 64 + lane];
        pd[hh] = v * ahat_next[256 + hh * 64 + lane];
    }
#pragma unroll
    for (int off = 1; off < 64; off <<= 1) {
#pragma unroll
        for (int hh = 0; hh < 4; ++hh) {
            ps[hh] += __shfl_xor(ps[hh], off);
            pd[hh] += __shfl_xor(pd[hh], off);
        }
    }
    if (lane == 0) {
        ((float4*)es)[node] = make_float4(ps[0], ps[1], ps[2], ps[3]);
        ((float4*)ed)[node] = make_float4(pd[0], pd[1], pd[2], pd[3]);
    }
}

// final BN apply (layer 2) fused with pooling partials.
// Block = 256 threads = 8 nodes x 32 ch. batch sorted -> block rarely spans 2 graphs.
__global__ void __launch_bounds__(256) k_bn_apply32_pool(const float* __restrict__ hnext,
                                                         const float* __restrict__ bn,
                                                         const float* __restrict__ g,
                                                         const float* __restrict__ be,
                                                         const int* __restrict__ batch,
                                                         float* __restrict__ out_h,
                                                         float* __restrict__ gsum,
                                                         unsigned* __restrict__ gmaxe) {
    int tid = threadIdx.x;
    int i = blockIdx.x * 256 + tid;   // exactly kN*32 threads
    int n = i >> 5, c = i & 31;
    float mu = bn[c] * (1.f / kN);
    float var = bn[32 + c] * (1.f / kN) - mu * mu;
    float v = g[c] * (hnext[i] - mu) * rsqrtf(var + 1e-5f) + be[c];
    out_h[i] = v;

    __shared__ float ls[256];
    ls[tid] = v;
    __syncthreads();
    int nb0 = blockIdx.x * 8;
    int gfirst = batch[nb0], glast = batch[nb0 + 7];
    if (gfirst == glast) {
        if (tid < 32) {
            float s = 0.f;
            unsigned me = 0u;
#pragma unroll
            for (int r = 0; r < 8; ++r) {
                float vv = ls[r * 32 + tid];
                s += vv;
                unsigned e = enc_f(vv);
                me = (e > me) ? e : me;
            }
            atomicAdd(&gsum[gfirst * 32 + tid], s);
            atomicMax(&gmaxe[gfirst * 32 + tid], me);
        }
    } else {
        int gg = batch[n];
        atomicAdd(&gsum[gg * 32 + c], v);
        atomicMax(&gmaxe[gg * 32 + c], enc_f(v));
    }
}

// finalize pooling + both MLP heads (single block)
__global__ void __launch_bounds__(256) k_finish(const float* __restrict__ gsum,
                                                const unsigned* __restrict__ gmaxe,
                                                const int* __restrict__ batch,
                                                const float* __restrict__ ew1,
                                                const float* __restrict__ eb1,
                                                const float* __restrict__ ew2,
                                                const float* __restrict__ eb2,
                                                const float* __restrict__ mw1,
                                                const float* __restrict__ mb1,
                                                const float* __restrict__ mw2,
                                                const float* __restrict__ mb2,
                                                float* __restrict__ out_gemb,
                                                float* __restrict__ out_eth,
                                                float* __restrict__ out_man) {
    __shared__ int bound[kG + 1];
    __shared__ float ge[kG * 32];
    int tid = threadIdx.x;
    if (tid <= kG) {
        int lo = 0, hi = kN;
        while (lo < hi) { int mid = (lo + hi) >> 1; if (batch[mid] < tid) lo = mid + 1; else hi = mid; }
        bound[tid] = lo;
    }
    __syncthreads();
    for (int j = tid; j < kG * 32; j += 256) {
        int gg = j >> 5;
        int cnt = bound[gg + 1] - bound[gg];
        float sum = gsum[j];
        float mx = (cnt > 0) ? dec_f(gmaxe[j]) : 0.f;
        float mean = sum / fmaxf((float)cnt, 1.f);
        float e = (mean + mx + sum) * (1.f / 3.f);
        ge[j] = e;
        out_gemb[j] = e;
    }
    __syncthreads();
    if (tid < kG) {
        const float* row = &ge[tid * 32];
        float acc_e = eb2[0], acc_m = mb2[0];
#pragma unroll 4
        for (int j = 0; j < 16; ++j) {
            float he = eb1[j], hm = mb1[j];
            for (int k = 0; k < 32; ++k) {
                float v = row[k];
                he += v * ew1[k * 16 + j];
                hm += v * mw1[k * 16 + j];
            }
            acc_e += fmaxf(he, 0.f) * ew2[j];
            acc_m += fmaxf(hm, 0.f) * mw2[j];
        }
        out_eth[tid] = 1.f / (1.f + expf(-acc_e));
        out_man[tid] = 1.f / (1.f + expf(-acc_m));
    }
}

extern "C" void kernel_launch(void* const* d_in, const int* in_sizes, int n_in,
                              void* d_out, int out_size, void* d_ws, size_t ws_size,
                              hipStream_t stream) {
    const float* x     = (const float*)d_in[0];
    const int*   ei    = (const int*)d_in[1];
    const int*   batch = (const int*)d_in[2];
    const float* enc_w = (const float*)d_in[3];
    const float* enc_b = (const float*)d_in[4];

    float* ws = (float*)d_ws;
    ushort*   hcur  = (ushort*)(ws + OFF_HCUR);
    float*    hnext = ws + OFF_HNEXT;
    ushort*   z     = (ushort*)(ws + OFF_Z);
    float*    es    = ws + OFF_ES;
    float*    ed    = ws + OFF_ED;
    int*      rowptr= (int*)(ws + OFF_ROWPTR);
    int*      cursor= (int*)(ws + OFF_CURSOR);
    int*      srcc  = (int*)(ws + OFF_SRC);
    ushort*   Wt2   = (ushort*)(ws + OFF_WT2);
    float*    ahat  = ws + OFF_AHAT;
    float*    bn    = ws + OFF_BN;
    float*    gsum  = ws + OFF_GPOOL;
    unsigned* gmaxe = (unsigned*)(ws + OFF_GPOOL + 1600);
    int*      spart = (int*)(ws + OFF_SPART);
    float*    part2 = ws + OFF_PART2;

    float* out      = (float*)d_out;
    float* out_h    = out;                 // N*32
    float* out_gemb = out + 1600000;       // G*32
    float* out_eth  = out + 1601600;       // G
    float* out_man  = out + 1601650;       // G

    // ---- init ----
    hipMemsetAsync(cursor, 0, kN * sizeof(int), stream);
    hipMemsetAsync(ws + OFF_GPOOL, 0, 3200 * sizeof(float), stream);

    // ---- CSR build (once) ----
    k_hist<<<(kET + 255) / 256, 256, 0, stream>>>(ei, cursor);
    k_scan_local<<<kScanBlocks, 1024, 0, stream>>>(cursor, rowptr, spart);
    k_scan_part<<<1, 64, 0, stream>>>(spart);
    k_scan_add<<<kScanBlocks, 1024, 0, stream>>>(cursor, rowptr, spart);
    k_scatter<<<(kET + 255) / 256, 256, 0, stream>>>(ei, cursor, srcc);

    // ---- weight prep ----
    k_prep_all<<<163, 256, 0, stream>>>((const float*)d_in[5], (const float*)d_in[11],
                                        (const float*)d_in[17], (const float*)d_in[6],
                                        (const float*)d_in[12], (const float*)d_in[18],
                                        (const float*)d_in[7], (const float*)d_in[13],
                                        (const float*)d_in[19], ahat, Wt2);

    // ---- encoder + layer-0 attention terms ----
    k_encoder_att<<<kN / 4, 256, 0, stream>>>(x, enc_w, enc_b, ahat, hcur, es, ed);

    for (int l = 0; l < 3; ++l) {
        const float* gam = (const float*)d_in[9 + 6 * l];
        const float* bet = (const float*)d_in[10 + 6 * l];
        const ushort* Wt2l = Wt2 + l * 16384;

        k_gat<<<kN / 4, 256, 0, stream>>>(rowptr, srcc, es, ed, hcur, z);

        if (l < 2) {
            k_zgemm<64><<<1563, 256, 0, stream>>>(z, Wt2l, hnext, part2);
            k_bnred<64><<<1, 256, 0, stream>>>(part2, 1563, bn);
            k_bn_apply_att<<<kN / 4, 256, 0, stream>>>(hnext, bn, gam, bet,
                                                       ahat + (l + 1) * 512, hcur, es, ed);
        } else {
            k_zgemm<32><<<782, 256, 0, stream>>>(z, Wt2l, hnext, part2);
            k_bnred<32><<<1, 256, 0, stream>>>(part2, 782, bn);
            k_bn_apply32_pool<<<kN * 32 / 256, 256, 0, stream>>>(hnext, bn, gam, bet,
                                                                 batch, out_h, gsum, gmaxe);
        }
    }

    k_finish<<<1, 256, 0, stream>>>(gsum, gmaxe, batch,
                                    (const float*)d_in[23], (const float*)d_in[24],
                                    (const float*)d_in[25], (const float*)d_in[26],
                                    (const float*)d_in[27], (const float*)d_in[28],
                                    (const float*)d_in[29], (const float*)d_in[30],
                                    out_gemb, out_eth, out_man);
}

// Round 11
// 535.048 us; speedup vs baseline: 1.6914x; 1.6914x over previous
//
#include <hip/hip_runtime.h>
#include <math.h>

// Problem constants
constexpr int kN  = 50000;     // nodes
constexpr int kE  = 600000;    // raw edges
constexpr int kET = 650000;    // edges + self loops
constexpr int kG  = 50;        // graphs
constexpr int kH  = 4;         // heads

// ws layout (float-slot offsets)
constexpr size_t OFF_HCUR   = 0;           // N*64 bf16  -> 1.6M float slots
constexpr size_t OFF_HNEXT  = 1600000;     // N*64 f32   -> 3.2M
constexpr size_t OFF_Z      = 4800000;     // N*256 bf16 -> 6.4M slots
constexpr size_t OFF_ES     = 11200000;    // N*4 f32
constexpr size_t OFF_ED     = 11400000;    // N*4 f32
constexpr size_t OFF_ROWPTR = 14200000;    // (N+1) ints
constexpr size_t OFF_CURSOR = 14260000;    // N ints
constexpr size_t OFF_SRC    = 14320000;    // ET ints
constexpr size_t OFF_WT2    = 14970000;    // 3 layers x 16384 bf16
constexpr size_t OFF_AHAT   = 15000000;    // 3 layers x 512 f32
constexpr size_t OFF_BN     = 15002000;    // 3 layers x 128 f32 (sum, sumsq) -- atomically accumulated
constexpr size_t OFF_GPOOL  = 15003000;    // gsum[1600] f32 + gmaxe[1600] u32
constexpr size_t OFF_SPART  = 15008000;    // 64 ints (scan partials)

constexpr int kScanBlocks = (kN + 1023) / 1024;  // 49

typedef __bf16 bf16x8 __attribute__((ext_vector_type(8)));
typedef float  f32x4  __attribute__((ext_vector_type(4)));

__device__ inline ushort f2b(float f) {  // RNE float->bf16 bits
    unsigned u = __float_as_uint(f);
    return (ushort)((u + 0x7FFFu + ((u >> 16) & 1u)) >> 16);
}
__device__ inline float b2f(ushort u) {
    return __uint_as_float(((unsigned)u) << 16);
}
__device__ inline unsigned enc_f(float f) {  // monotone float->uint
    unsigned b = __float_as_uint(f);
    return (b & 0x80000000u) ? ~b : (b | 0x80000000u);
}
__device__ inline float dec_f(unsigned u) {
    return __uint_as_float((u & 0x80000000u) ? (u & 0x7FFFFFFFu) : ~u);
}

__device__ inline void edge_pair(const int* __restrict__ ei, int e, int& src, int& dst) {
    if (e < kE) { src = ei[e]; dst = ei[kE + e]; }
    else        { src = e - kE; dst = e - kE; }
}

// ---------------- CSR build (once per launch) ----------------
__global__ void k_hist(const int* __restrict__ ei, int* __restrict__ counts) {
    int e = blockIdx.x * blockDim.x + threadIdx.x;
    if (e >= kET) return;
    int src, dst;
    edge_pair(ei, e, src, dst);
    atomicAdd(&counts[dst], 1);
}

__global__ void __launch_bounds__(1024) k_scan_local(const int* __restrict__ counts,
                                                     int* __restrict__ rowptr,
                                                     int* __restrict__ partials) {
    int tid = threadIdx.x;
    int idx = blockIdx.x * 1024 + tid;
    int val = (idx < kN) ? counts[idx] : 0;
    int lane = tid & 63, w = tid >> 6;
    int x = val;
#pragma unroll
    for (int off = 1; off < 64; off <<= 1) {
        int t = __shfl_up(x, off);
        if (lane >= off) x += t;
    }
    __shared__ int wsum[16];
    if (lane == 63) wsum[w] = x;
    __syncthreads();
    if (w == 0 && lane < 16) {
        int y = wsum[lane];
#pragma unroll
        for (int off = 1; off < 16; off <<= 1) {
            int t = __shfl_up(y, off);
            if (lane >= off) y += t;
        }
        wsum[lane] = y;
    }
    __syncthreads();
    int incl = x + (w > 0 ? wsum[w - 1] : 0);
    if (idx < kN) rowptr[idx + 1] = incl;
    if (tid == 1023) partials[blockIdx.x] = incl;
}

__global__ void k_scan_part(int* __restrict__ partials) {
    int lane = threadIdx.x;
    int v = (lane < kScanBlocks) ? partials[lane] : 0;
    int x = v;
#pragma unroll
    for (int off = 1; off < 64; off <<= 1) {
        int t = __shfl_up(x, off);
        if (lane >= off) x += t;
    }
    if (lane < kScanBlocks) partials[lane] = x - v;
}

__global__ void __launch_bounds__(1024) k_scan_add(int* __restrict__ cursor,
                                                   int* __restrict__ rowptr,
                                                   const int* __restrict__ partials) {
    int idx = blockIdx.x * 1024 + threadIdx.x;
    if (idx >= kN) return;
    int incl = rowptr[idx + 1] + partials[blockIdx.x];
    rowptr[idx + 1] = incl;
    int val = cursor[idx];
    cursor[idx] = incl - val;
    if (idx == 0) rowptr[0] = 0;
}

__global__ void k_scatter(const int* __restrict__ ei, int* __restrict__ cursor,
                          int* __restrict__ src_csr) {
    int e = blockIdx.x * blockDim.x + threadIdx.x;
    if (e >= kET) return;
    int src, dst;
    edge_pair(ei, e, src, dst);
    int pos = atomicAdd(&cursor[dst], 1);
    src_csr[pos] = src;
}

// ---------------- weight prep: all 3 layers in one dispatch ----------------
__global__ void k_prep_all(const float* __restrict__ w0, const float* __restrict__ w1,
                           const float* __restrict__ w2, const float* __restrict__ as0,
                           const float* __restrict__ as1, const float* __restrict__ as2,
                           const float* __restrict__ ad0, const float* __restrict__ ad1,
                           const float* __restrict__ ad2, float* __restrict__ ahat,
                           ushort* __restrict__ Wt2) {
    int b = blockIdx.x;
    if (b < 3) {
        const float* W  = (b == 0) ? w0 : (b == 1) ? w1 : w2;
        const float* As = (b == 0) ? as0 : (b == 1) ? as1 : as2;
        const float* Ad = (b == 0) ? ad0 : (b == 1) ? ad1 : ad2;
        int dout = (b == 2) ? 32 : 64;
        int i = threadIdx.x;
        int h = i >> 6, k = i & 63;
        const float* wr = W + (size_t)k * (4 * dout) + h * dout;
        float s1 = 0.f, s2 = 0.f;
        for (int c = 0; c < dout; ++c) {
            float w = wr[c];
            s1 += w * As[h * dout + c];
            s2 += w * Ad[h * dout + c];
        }
        ahat[b * 512 + i] = s1;
        ahat[b * 512 + 256 + i] = s2;
    } else {
        int i = (b - 3) * 256 + threadIdx.x;   // over 40960
        if (i >= 40960) return;
        int l, li;
        if (i < 16384)      { l = 0; li = i; }
        else if (i < 32768) { l = 1; li = i - 16384; }
        else                { l = 2; li = i - 32768; }
        int dout = (l == 2) ? 32 : 64;
        const float* W = (l == 0) ? w0 : (l == 1) ? w1 : w2;
        int c = li >> 8, kk = li & 255;
        int h = kk >> 6, k = kk & 63;
        Wt2[l * 16384 + li] = f2b(W[(size_t)k * (4 * dout) + h * dout + c]);
    }
}

// ---------------- encoder + fused layer-0 es/ed ----------------
__global__ void __launch_bounds__(256) k_encoder_att(const float* __restrict__ x,
                                                     const float* __restrict__ w,
                                                     const float* __restrict__ b,
                                                     const float* __restrict__ ahat0,
                                                     ushort* __restrict__ h,
                                                     float* __restrict__ es,
                                                     float* __restrict__ ed) {
    int node = blockIdx.x * 4 + (threadIdx.x >> 6);
    int lane = threadIdx.x & 63;
    float acc = b[lane];
#pragma unroll
    for (int k = 0; k < 5; ++k) acc += x[node * 5 + k] * w[k * 64 + lane];
    h[(size_t)node * 64 + lane] = f2b(acc);

    float ps[4], pd[4];
#pragma unroll
    for (int hh = 0; hh < 4; ++hh) {
        ps[hh] = acc * ahat0[hh * 64 + lane];
        pd[hh] = acc * ahat0[256 + hh * 64 + lane];
    }
#pragma unroll
    for (int off = 1; off < 64; off <<= 1) {
#pragma unroll
        for (int hh = 0; hh < 4; ++hh) {
            ps[hh] += __shfl_xor(ps[hh], off);
            pd[hh] += __shfl_xor(pd[hh], off);
        }
    }
    if (lane == 0) {
        ((float4*)es)[node] = make_float4(ps[0], ps[1], ps[2], ps[3]);
        ((float4*)ed)[node] = make_float4(pd[0], pd[1], pd[2], pd[3]);
    }
}

// Fused edge-softmax + aggregation. One wave per dst.
__global__ void __launch_bounds__(256) k_gat(const int* __restrict__ rowptr,
                                             const int* __restrict__ srcc,
                                             const float* __restrict__ es,
                                             const float* __restrict__ ed,
                                             const ushort* __restrict__ h,
                                             ushort* __restrict__ z) {
    int wid = threadIdx.x >> 6;
    int lane = threadIdx.x & 63;
    int dst = blockIdx.x * 4 + wid;   // kN % 4 == 0
    int start = rowptr[dst], end = rowptr[dst + 1];
    int deg = end - start;

    int e_l = lane >> 2, hh = lane & 3;    // score mapping
    int q = lane >> 4, c4 = lane & 15;     // gather mapping

    float edv = ed[dst * 4 + hh];
    float acc[4][4] = {};
    float s;

    if (deg <= 16) {
        int pos = start + e_l;
        int psafe = (pos < end) ? pos : start;
        int src = srcc[psafe];
        float v = es[src * 4 + hh] + edv;
        v = (v >= 0.f) ? v : 0.2f * v;
        if (pos >= end) v = -3e38f;

        uint2 hv[4];
#pragma unroll
        for (int t = 0; t < 4; ++t) {
            int p2 = start + t * 4 + q;
            int p2s = (p2 < end) ? p2 : start;
            int s2 = srcc[p2s];
            hv[t] = *reinterpret_cast<const uint2*>(h + (size_t)s2 * 64 + c4 * 4);
        }

        float cm = v;
        cm = fmaxf(cm, __shfl_xor(cm, 4));
        cm = fmaxf(cm, __shfl_xor(cm, 8));
        cm = fmaxf(cm, __shfl_xor(cm, 16));
        cm = fmaxf(cm, __shfl_xor(cm, 32));
        float p = __expf(v - cm);
        float cs = p;
        cs += __shfl_xor(cs, 4);
        cs += __shfl_xor(cs, 8);
        cs += __shfl_xor(cs, 16);
        cs += __shfl_xor(cs, 32);
        s = cs;

#pragma unroll
        for (int t = 0; t < 4; ++t) {
            int el = t * 4 + q;
            float p0 = __shfl(p, (el << 2) | 0);
            float p1 = __shfl(p, (el << 2) | 1);
            float p2 = __shfl(p, (el << 2) | 2);
            float p3 = __shfl(p, (el << 2) | 3);
            float c0 = __uint_as_float(hv[t].x << 16);
            float c1 = __uint_as_float(hv[t].x & 0xFFFF0000u);
            float c2 = __uint_as_float(hv[t].y << 16);
            float c3 = __uint_as_float(hv[t].y & 0xFFFF0000u);
            acc[0][0] += p0 * c0; acc[0][1] += p0 * c1; acc[0][2] += p0 * c2; acc[0][3] += p0 * c3;
            acc[1][0] += p1 * c0; acc[1][1] += p1 * c1; acc[1][2] += p1 * c2; acc[1][3] += p1 * c3;
            acc[2][0] += p2 * c0; acc[2][1] += p2 * c1; acc[2][2] += p2 * c2; acc[2][3] += p2 * c3;
            acc[3][0] += p3 * c0; acc[3][1] += p3 * c1; acc[3][2] += p3 * c2; acc[3][3] += p3 * c3;
        }
    } else {
        float m = -3e38f;
        s = 0.f;
        for (int cs0 = start; cs0 < end; cs0 += 16) {
            int pos = cs0 + e_l;
            int psafe = (pos < end) ? pos : start;
            int src = srcc[psafe];
            float v = es[src * 4 + hh] + edv;
            v = (v >= 0.f) ? v : 0.2f * v;
            if (pos >= end) v = -3e38f;

            float cm = v;
            cm = fmaxf(cm, __shfl_xor(cm, 4));
            cm = fmaxf(cm, __shfl_xor(cm, 8));
            cm = fmaxf(cm, __shfl_xor(cm, 16));
            cm = fmaxf(cm, __shfl_xor(cm, 32));
            float mn = fmaxf(m, cm);
            float scale = __expf(m - mn);
            float p = __expf(v - mn);
            float cth = p;
            cth += __shfl_xor(cth, 4);
            cth += __shfl_xor(cth, 8);
            cth += __shfl_xor(cth, 16);
            cth += __shfl_xor(cth, 32);
            s = s * scale + cth;
            m = mn;

            float sc0 = __shfl(scale, 0), sc1 = __shfl(scale, 1);
            float sc2 = __shfl(scale, 2), sc3 = __shfl(scale, 3);
#pragma unroll
            for (int c = 0; c < 4; ++c) {
                acc[0][c] *= sc0; acc[1][c] *= sc1; acc[2][c] *= sc2; acc[3][c] *= sc3;
            }
#pragma unroll
            for (int t = 0; t < 4; ++t) {
                int el = t * 4 + q;
                int p2 = cs0 + el;
                int p2s = (p2 < end) ? p2 : start;
                int s2 = srcc[p2s];
                uint2 hv = *reinterpret_cast<const uint2*>(h + (size_t)s2 * 64 + c4 * 4);
                float p0 = __shfl(p, (el << 2) | 0);
                float p1 = __shfl(p, (el << 2) | 1);
                float p2f = __shfl(p, (el << 2) | 2);
                float p3 = __shfl(p, (el << 2) | 3);
                float c0 = __uint_as_float(hv.x << 16);
                float c1 = __uint_as_float(hv.x & 0xFFFF0000u);
                float c2 = __uint_as_float(hv.y << 16);
                float c3 = __uint_as_float(hv.y & 0xFFFF0000u);
                acc[0][0] += p0 * c0;  acc[0][1] += p0 * c1;  acc[0][2] += p0 * c2;  acc[0][3] += p0 * c3;
                acc[1][0] += p1 * c0;  acc[1][1] += p1 * c1;  acc[1][2] += p1 * c2;  acc[1][3] += p1 * c3;
                acc[2][0] += p2f * c0; acc[2][1] += p2f * c1; acc[2][2] += p2f * c2; acc[2][3] += p2f * c3;
                acc[3][0] += p3 * c0;  acc[3][1] += p3 * c1;  acc[3][2] += p3 * c2;  acc[3][3] += p3 * c3;
            }
        }
    }

    float myinv = 0.25f / (s + 1e-16f);
    float inv0 = __shfl(myinv, 0), inv1 = __shfl(myinv, 1);
    float inv2 = __shfl(myinv, 2), inv3 = __shfl(myinv, 3);
#pragma unroll
    for (int c = 0; c < 4; ++c) {
        acc[0][c] *= inv0; acc[1][c] *= inv1; acc[2][c] *= inv2; acc[3][c] *= inv3;
    }
#pragma unroll
    for (int j = 0; j < 4; ++j) {
#pragma unroll
        for (int c = 0; c < 4; ++c) {
            float v = acc[j][c];
            v += __shfl_xor(v, 16);
            v += __shfl_xor(v, 32);
            acc[j][c] = v;
        }
    }
    if (q == 0) {
        ushort* zr = z + (size_t)dst * 256 + c4 * 4;
#pragma unroll
        for (int j = 0; j < 4; ++j) {
            ushort4 o;
            o.x = f2b(acc[j][0]); o.y = f2b(acc[j][1]);
            o.z = f2b(acc[j][2]); o.w = f2b(acc[j][3]);
            *reinterpret_cast<ushort4*>(zr + j * 64) = o;
        }
    }
}

// MFMA GEMM with fused BN-stat accumulation (LDS combine -> 2*DOUT atomicAdds per block).
template <int DOUT>
__global__ void __launch_bounds__(256) k_zgemm(const ushort* __restrict__ z,
                                               const ushort* __restrict__ Wt2l,
                                               float* __restrict__ hnext,
                                               float* __restrict__ bnl) {
    constexpr int NG = DOUT / 32;
    constexpr int W = 2 * DOUT;
    __shared__ float pl[4][W];
    int tid = threadIdx.x;
    int widx = tid >> 6, lane = tid & 63;
    int wid = blockIdx.x * 4 + widx;
    int mtile = wid / NG;
    int ng = wid - mtile * NG;
    bool active = (mtile < kN / 16);
    int m0 = mtile * 16;
    int n0 = ng * 32;

    int row = lane & 15;
    int k0  = (lane >> 4) * 8;

    // zero-init LDS partials (each wave only writes its own n0 half later)
    for (int j = tid; j < 4 * W; j += 256) (&pl[0][0])[j] = 0.f;

    f32x4 acc0 = {0.f, 0.f, 0.f, 0.f};
    f32x4 acc1 = {0.f, 0.f, 0.f, 0.f};
    if (active) {
        const ushort* za = z + (size_t)(m0 + row) * 256 + k0;
        bf16x8 a[8];
#pragma unroll
        for (int ks = 0; ks < 8; ++ks)
            a[ks] = *reinterpret_cast<const bf16x8*>(za + ks * 32);

        const ushort* wb0 = Wt2l + (size_t)(n0 + row) * 256 + k0;
        const ushort* wb1 = wb0 + 16 * 256;
#pragma unroll
        for (int ks = 0; ks < 8; ++ks) {
            bf16x8 b0 = *reinterpret_cast<const bf16x8*>(wb0 + ks * 32);
            bf16x8 b1 = *reinterpret_cast<const bf16x8*>(wb1 + ks * 32);
            acc0 = __builtin_amdgcn_mfma_f32_16x16x32_bf16(a[ks], b0, acc0, 0, 0, 0);
            acc1 = __builtin_amdgcn_mfma_f32_16x16x32_bf16(a[ks], b1, acc1, 0, 0, 0);
        }

        int col = lane & 15;
        int r0  = (lane >> 4) * 4;
#pragma unroll
        for (int r = 0; r < 4; ++r) {
            hnext[(size_t)(m0 + r0 + r) * DOUT + n0 + col]      = acc0[r];
            hnext[(size_t)(m0 + r0 + r) * DOUT + n0 + 16 + col] = acc1[r];
        }
    }

    // per-wave column stats (zeros if inactive)
    float s0 = 0.f, q0 = 0.f, s1 = 0.f, q1 = 0.f;
#pragma unroll
    for (int r = 0; r < 4; ++r) {
        s0 += acc0[r]; q0 += acc0[r] * acc0[r];
        s1 += acc1[r]; q1 += acc1[r] * acc1[r];
    }
    s0 += __shfl_xor(s0, 16); s0 += __shfl_xor(s0, 32);
    q0 += __shfl_xor(q0, 16); q0 += __shfl_xor(q0, 32);
    s1 += __shfl_xor(s1, 16); s1 += __shfl_xor(s1, 32);
    q1 += __shfl_xor(q1, 16); q1 += __shfl_xor(q1, 32);
    __syncthreads();   // init complete before per-wave writes
    if (lane < 16) {
        pl[widx][n0 + lane]             = s0;
        pl[widx][DOUT + n0 + lane]      = q0;
        pl[widx][n0 + 16 + lane]        = s1;
        pl[widx][DOUT + n0 + 16 + lane] = q1;
    }
    __syncthreads();
    if (tid < W) {
        float t = pl[0][tid] + pl[1][tid] + pl[2][tid] + pl[3][tid];
        atomicAdd(&bnl[tid], t);
    }
}

// BN apply (layers 0,1) fused with NEXT layer's es/ed
__global__ void __launch_bounds__(256) k_bn_apply_att(const float* __restrict__ hnext,
                                                      const float* __restrict__ bn,
                                                      const float* __restrict__ g,
                                                      const float* __restrict__ be,
                                                      const float* __restrict__ ahat_next,
                                                      ushort* __restrict__ hcur,
                                                      float* __restrict__ es,
                                                      float* __restrict__ ed) {
    int node = blockIdx.x * 4 + (threadIdx.x >> 6);
    int lane = threadIdx.x & 63;
    float mu = bn[lane] * (1.f / kN);
    float var = bn[64 + lane] * (1.f / kN) - mu * mu;
    float v = g[lane] * (hnext[(size_t)node * 64 + lane] - mu) * rsqrtf(var + 1e-5f) + be[lane];
    v = fmaxf(v, 0.f);
    hcur[(size_t)node * 64 + lane] = f2b(v);

    float ps[4], pd[4];
#pragma unroll
    for (int hh = 0; hh < 4; ++hh) {
        ps[hh] = v * ahat_next[hh * 64 + lane];
        pd[hh] = v * ahat_next[256 + hh * 64 + lane];
    }
#pragma unroll
    for (int off = 1; off < 64; off <<= 1) {
#pragma unroll
        for (int hh = 0; hh < 4; ++hh) {
            ps[hh] += __shfl_xor(ps[hh], off);
            pd[hh] += __shfl_xor(pd[hh], off);
        }
    }
    if (lane == 0) {
        ((float4*)es)[node] = make_float4(ps[0], ps[1], ps[2], ps[3]);
        ((float4*)ed)[node] = make_float4(pd[0], pd[1], pd[2], pd[3]);
    }
}

// final BN apply (layer 2) fused with pooling partials.
__global__ void __launch_bounds__(256) k_bn_apply32_pool(const float* __restrict__ hnext,
                                                         const float* __restrict__ bn,
                                                         const float* __restrict__ g,
                                                         const float* __restrict__ be,
                                                         const int* __restrict__ batch,
                                                         float* __restrict__ out_h,
                                                         float* __restrict__ gsum,
                                                         unsigned* __restrict__ gmaxe) {
    int tid = threadIdx.x;
    int i = blockIdx.x * 256 + tid;   // exactly kN*32 threads
    int n = i >> 5, c = i & 31;
    float mu = bn[c] * (1.f / kN);
    float var = bn[32 + c] * (1.f / kN) - mu * mu;
    float v = g[c] * (hnext[i] - mu) * rsqrtf(var + 1e-5f) + be[c];
    out_h[i] = v;

    __shared__ float ls[256];
    ls[tid] = v;
    __syncthreads();
    int nb0 = blockIdx.x * 8;
    int gfirst = batch[nb0], glast = batch[nb0 + 7];
    if (gfirst == glast) {
        if (tid < 32) {
            float s = 0.f;
            unsigned me = 0u;
#pragma unroll
            for (int r = 0; r < 8; ++r) {
                float vv = ls[r * 32 + tid];
                s += vv;
                unsigned e = enc_f(vv);
                me = (e > me) ? e : me;
            }
            atomicAdd(&gsum[gfirst * 32 + tid], s);
            atomicMax(&gmaxe[gfirst * 32 + tid], me);
        }
    } else {
        int gg = batch[n];
        atomicAdd(&gsum[gg * 32 + c], v);
        atomicMax(&gmaxe[gg * 32 + c], enc_f(v));
    }
}

// finalize pooling + both MLP heads (single block)
__global__ void __launch_bounds__(256) k_finish(const float* __restrict__ gsum,
                                                const unsigned* __restrict__ gmaxe,
                                                const int* __restrict__ batch,
                                                const float* __restrict__ ew1,
                                                const float* __restrict__ eb1,
                                                const float* __restrict__ ew2,
                                                const float* __restrict__ eb2,
                                                const float* __restrict__ mw1,
                                                const float* __restrict__ mb1,
                                                const float* __restrict__ mw2,
                                                const float* __restrict__ mb2,
                                                float* __restrict__ out_gemb,
                                                float* __restrict__ out_eth,
                                                float* __restrict__ out_man) {
    __shared__ int bound[kG + 1];
    __shared__ float ge[kG * 32];
    int tid = threadIdx.x;
    if (tid <= kG) {
        int lo = 0, hi = kN;
        while (lo < hi) { int mid = (lo + hi) >> 1; if (batch[mid] < tid) lo = mid + 1; else hi = mid; }
        bound[tid] = lo;
    }
    __syncthreads();
    for (int j = tid; j < kG * 32; j += 256) {
        int gg = j >> 5;
        int cnt = bound[gg + 1] - bound[gg];
        float sum = gsum[j];
        float mx = (cnt > 0) ? dec_f(gmaxe[j]) : 0.f;
        float mean = sum / fmaxf((float)cnt, 1.f);
        float e = (mean + mx + sum) * (1.f / 3.f);
        ge[j] = e;
        out_gemb[j] = e;
    }
    __syncthreads();
    if (tid < kG) {
        const float* row = &ge[tid * 32];
        float acc_e = eb2[0], acc_m = mb2[0];
#pragma unroll 4
        for (int j = 0; j < 16; ++j) {
            float he = eb1[j], hm = mb1[j];
            for (int k = 0; k < 32; ++k) {
                float v = row[k];
                he += v * ew1[k * 16 + j];
                hm += v * mw1[k * 16 + j];
            }
            acc_e += fmaxf(he, 0.f) * ew2[j];
            acc_m += fmaxf(hm, 0.f) * mw2[j];
        }
        out_eth[tid] = 1.f / (1.f + expf(-acc_e));
        out_man[tid] = 1.f / (1.f + expf(-acc_m));
    }
}

extern "C" void kernel_launch(void* const* d_in, const int* in_sizes, int n_in,
                              void* d_out, int out_size, void* d_ws, size_t ws_size,
                              hipStream_t stream) {
    const float* x     = (const float*)d_in[0];
    const int*   ei    = (const int*)d_in[1];
    const int*   batch = (const int*)d_in[2];
    const float* enc_w = (const float*)d_in[3];
    const float* enc_b = (const float*)d_in[4];

    float* ws = (float*)d_ws;
    ushort*   hcur  = (ushort*)(ws + OFF_HCUR);
    float*    hnext = ws + OFF_HNEXT;
    ushort*   z     = (ushort*)(ws + OFF_Z);
    float*    es    = ws + OFF_ES;
    float*    ed    = ws + OFF_ED;
    int*      rowptr= (int*)(ws + OFF_ROWPTR);
    int*      cursor= (int*)(ws + OFF_CURSOR);
    int*      srcc  = (int*)(ws + OFF_SRC);
    ushort*   Wt2   = (ushort*)(ws + OFF_WT2);
    float*    ahat  = ws + OFF_AHAT;
    float*    bn    = ws + OFF_BN;     // 3 x 128
    float*    gsum  = ws + OFF_GPOOL;
    unsigned* gmaxe = (unsigned*)(ws + OFF_GPOOL + 1600);
    int*      spart = (int*)(ws + OFF_SPART);

    float* out      = (float*)d_out;
    float* out_h    = out;                 // N*32
    float* out_gemb = out + 1600000;       // G*32
    float* out_eth  = out + 1601600;       // G
    float* out_man  = out + 1601650;       // G

    // ---- init: cursor + bn(3x128) + gpool(3200) ----
    hipMemsetAsync(cursor, 0, kN * sizeof(int), stream);
    hipMemsetAsync(ws + OFF_BN, 0, 4200 * sizeof(float), stream);  // OFF_BN..OFF_GPOOL+3200

    // ---- CSR build (once) ----
    k_hist<<<(kET + 255) / 256, 256, 0, stream>>>(ei, cursor);
    k_scan_local<<<kScanBlocks, 1024, 0, stream>>>(cursor, rowptr, spart);
    k_scan_part<<<1, 64, 0, stream>>>(spart);
    k_scan_add<<<kScanBlocks, 1024, 0, stream>>>(cursor, rowptr, spart);
    k_scatter<<<(kET + 255) / 256, 256, 0, stream>>>(ei, cursor, srcc);

    // ---- weight prep ----
    k_prep_all<<<163, 256, 0, stream>>>((const float*)d_in[5], (const float*)d_in[11],
                                        (const float*)d_in[17], (const float*)d_in[6],
                                        (const float*)d_in[12], (const float*)d_in[18],
                                        (const float*)d_in[7], (const float*)d_in[13],
                                        (const float*)d_in[19], ahat, Wt2);

    // ---- encoder + layer-0 attention terms ----
    k_encoder_att<<<kN / 4, 256, 0, stream>>>(x, enc_w, enc_b, ahat, hcur, es, ed);

    for (int l = 0; l < 3; ++l) {
        const float* gam = (const float*)d_in[9 + 6 * l];
        const float* bet = (const float*)d_in[10 + 6 * l];
        const ushort* Wt2l = Wt2 + l * 16384;
        float* bnl = bn + l * 128;

        k_gat<<<kN / 4, 256, 0, stream>>>(rowptr, srcc, es, ed, hcur, z);

        if (l < 2) {
            k_zgemm<64><<<1563, 256, 0, stream>>>(z, Wt2l, hnext, bnl);
            k_bn_apply_att<<<kN / 4, 256, 0, stream>>>(hnext, bnl, gam, bet,
                                                       ahat + (l + 1) * 512, hcur, es, ed);
        } else {
            k_zgemm<32><<<782, 256, 0, stream>>>(z, Wt2l, hnext, bnl);
            k_bn_apply32_pool<<<kN * 32 / 256, 256, 0, stream>>>(hnext, bnl, gam, bet,
                                                                 batch, out_h, gsum, gmaxe);
        }
    }

    k_finish<<<1, 256, 0, stream>>>(gsum, gmaxe, batch,
                                    (const float*)d_in[23], (const float*)d_in[24],
                                    (const float*)d_in[25], (const float*)d_in[26],
                                    (const float*)d_in[27], (const float*)d_in[28],
                                    (const float*)d_in[29], (const float*)d_in[30],
                                    out_gemb, out_eth, out_man);
}

// Round 12
// 487.987 us; speedup vs baseline: 1.8546x; 1.0964x over previous
//
#include <hip/hip_runtime.h>
#include <math.h>

// Problem constants
constexpr int kN  = 50000;     // nodes
constexpr int kE  = 600000;    // raw edges
constexpr int kET = 650000;    // edges + self loops
constexpr int kG  = 50;        // graphs
constexpr int kH  = 4;         // heads
constexpr int kRep = 16;       // BN atomic replicas

// ws layout (float-slot offsets)
constexpr size_t OFF_HCUR   = 0;           // N*64 bf16
constexpr size_t OFF_HNEXT  = 1600000;     // N*64 f32
constexpr size_t OFF_Z      = 4800000;     // N*256 bf16
constexpr size_t OFF_ES     = 11200000;    // N*4 f32
constexpr size_t OFF_ED     = 11400000;    // N*4 f32
constexpr size_t OFF_ROWPTR = 14200000;    // (N+1) ints
constexpr size_t OFF_SRC    = 14320000;    // ET ints
constexpr size_t OFF_WT2    = 14970000;    // 3 x 16384 bf16
constexpr size_t OFF_AHAT   = 15000000;    // 3 x 512 f32
constexpr size_t OFF_SPART  = 15002000;    // 64 ints
// ---- contiguous zero-init region (single memset) ----
constexpr size_t OFF_CURSOR = 15010000;    // N ints
constexpr size_t OFF_BNREP  = 15060000;    // 3 x kRep x 128 f32 = 6144
constexpr size_t OFF_GPOOL  = 15066144;    // gsum[1600] + gmaxe[1600]
constexpr size_t kZeroEnd   = 15069344;

constexpr int kScanBlocks = (kN + 1023) / 1024;  // 49
constexpr int kHistBlocks = (kET + 255) / 256;   // 2540
constexpr int kPrepBlocks = 163;
constexpr int kEncBlocks  = kN / 4;              // 12500

typedef __bf16 bf16x8 __attribute__((ext_vector_type(8)));
typedef float  f32x4  __attribute__((ext_vector_type(4)));

__device__ inline ushort f2b(float f) {  // RNE float->bf16 bits
    unsigned u = __float_as_uint(f);
    return (ushort)((u + 0x7FFFu + ((u >> 16) & 1u)) >> 16);
}
__device__ inline float b2f(ushort u) {
    return __uint_as_float(((unsigned)u) << 16);
}
__device__ inline unsigned enc_f(float f) {  // monotone float->uint
    unsigned b = __float_as_uint(f);
    return (b & 0x80000000u) ? ~b : (b | 0x80000000u);
}
__device__ inline float dec_f(unsigned u) {
    return __uint_as_float((u & 0x80000000u) ? (u & 0x7FFFFFFFu) : ~u);
}

__device__ inline void edge_pair(const int* __restrict__ ei, int e, int& src, int& dst) {
    if (e < kE) { src = ei[e]; dst = ei[kE + e]; }
    else        { src = e - kE; dst = e - kE; }
}

// ---------------- fused: weight prep (blocks 0..162) + dst histogram ----------------
__global__ void k_histprep(const int* __restrict__ ei, int* __restrict__ counts,
                           const float* __restrict__ w0, const float* __restrict__ w1,
                           const float* __restrict__ w2, const float* __restrict__ as0,
                           const float* __restrict__ as1, const float* __restrict__ as2,
                           const float* __restrict__ ad0, const float* __restrict__ ad1,
                           const float* __restrict__ ad2, float* __restrict__ ahat,
                           ushort* __restrict__ Wt2) {
    int b = blockIdx.x;
    if (b < 3) {
        const float* W  = (b == 0) ? w0 : (b == 1) ? w1 : w2;
        const float* As = (b == 0) ? as0 : (b == 1) ? as1 : as2;
        const float* Ad = (b == 0) ? ad0 : (b == 1) ? ad1 : ad2;
        int dout = (b == 2) ? 32 : 64;
        int i = threadIdx.x;
        int h = i >> 6, k = i & 63;
        const float* wr = W + (size_t)k * (4 * dout) + h * dout;
        float s1 = 0.f, s2 = 0.f;
        for (int c = 0; c < dout; ++c) {
            float w = wr[c];
            s1 += w * As[h * dout + c];
            s2 += w * Ad[h * dout + c];
        }
        ahat[b * 512 + i] = s1;
        ahat[b * 512 + 256 + i] = s2;
    } else if (b < kPrepBlocks) {
        int i = (b - 3) * 256 + threadIdx.x;   // over 40960
        if (i >= 40960) return;
        int l, li;
        if (i < 16384)      { l = 0; li = i; }
        else if (i < 32768) { l = 1; li = i - 16384; }
        else                { l = 2; li = i - 32768; }
        int dout = (l == 2) ? 32 : 64;
        const float* W = (l == 0) ? w0 : (l == 1) ? w1 : w2;
        int c = li >> 8, kk = li & 255;
        int h = kk >> 6, k = kk & 63;
        Wt2[l * 16384 + li] = f2b(W[(size_t)k * (4 * dout) + h * dout + c]);
    } else {
        int e = (b - kPrepBlocks) * 256 + threadIdx.x;
        if (e >= kET) return;
        int src, dst;
        edge_pair(ei, e, src, dst);
        atomicAdd(&counts[dst], 1);
    }
}

__global__ void __launch_bounds__(1024) k_scan_local(const int* __restrict__ counts,
                                                     int* __restrict__ rowptr,
                                                     int* __restrict__ partials) {
    int tid = threadIdx.x;
    int idx = blockIdx.x * 1024 + tid;
    int val = (idx < kN) ? counts[idx] : 0;
    int lane = tid & 63, w = tid >> 6;
    int x = val;
#pragma unroll
    for (int off = 1; off < 64; off <<= 1) {
        int t = __shfl_up(x, off);
        if (lane >= off) x += t;
    }
    __shared__ int wsum[16];
    if (lane == 63) wsum[w] = x;
    __syncthreads();
    if (w == 0 && lane < 16) {
        int y = wsum[lane];
#pragma unroll
        for (int off = 1; off < 16; off <<= 1) {
            int t = __shfl_up(y, off);
            if (lane >= off) y += t;
        }
        wsum[lane] = y;
    }
    __syncthreads();
    int incl = x + (w > 0 ? wsum[w - 1] : 0);
    if (idx < kN) rowptr[idx + 1] = incl;
    if (tid == 1023) partials[blockIdx.x] = incl;
}

__global__ void k_scan_part(int* __restrict__ partials) {
    int lane = threadIdx.x;
    int v = (lane < kScanBlocks) ? partials[lane] : 0;
    int x = v;
#pragma unroll
    for (int off = 1; off < 64; off <<= 1) {
        int t = __shfl_up(x, off);
        if (lane >= off) x += t;
    }
    if (lane < kScanBlocks) partials[lane] = x - v;
}

__global__ void __launch_bounds__(1024) k_scan_add(int* __restrict__ cursor,
                                                   int* __restrict__ rowptr,
                                                   const int* __restrict__ partials) {
    int idx = blockIdx.x * 1024 + threadIdx.x;
    if (idx >= kN) return;
    int incl = rowptr[idx + 1] + partials[blockIdx.x];
    rowptr[idx + 1] = incl;
    int val = cursor[idx];
    cursor[idx] = incl - val;
    if (idx == 0) rowptr[0] = 0;
}

// ---------------- fused: encoder+layer0 es/ed (blocks 0..12499) + CSR scatter ----------------
__global__ void __launch_bounds__(256) k_scatter_enc(const int* __restrict__ ei,
                                                     int* __restrict__ cursor,
                                                     int* __restrict__ src_csr,
                                                     const float* __restrict__ x,
                                                     const float* __restrict__ w,
                                                     const float* __restrict__ b,
                                                     const float* __restrict__ ahat0,
                                                     ushort* __restrict__ h,
                                                     float* __restrict__ es,
                                                     float* __restrict__ ed) {
    if (blockIdx.x < kEncBlocks) {
        int node = blockIdx.x * 4 + (threadIdx.x >> 6);
        int lane = threadIdx.x & 63;
        float acc = b[lane];
#pragma unroll
        for (int k = 0; k < 5; ++k) acc += x[node * 5 + k] * w[k * 64 + lane];
        h[(size_t)node * 64 + lane] = f2b(acc);

        float ps[4], pd[4];
#pragma unroll
        for (int hh = 0; hh < 4; ++hh) {
            ps[hh] = acc * ahat0[hh * 64 + lane];
            pd[hh] = acc * ahat0[256 + hh * 64 + lane];
        }
#pragma unroll
        for (int off = 1; off < 64; off <<= 1) {
#pragma unroll
            for (int hh = 0; hh < 4; ++hh) {
                ps[hh] += __shfl_xor(ps[hh], off);
                pd[hh] += __shfl_xor(pd[hh], off);
            }
        }
        if (lane == 0) {
            ((float4*)es)[node] = make_float4(ps[0], ps[1], ps[2], ps[3]);
            ((float4*)ed)[node] = make_float4(pd[0], pd[1], pd[2], pd[3]);
        }
    } else {
        int e = (blockIdx.x - kEncBlocks) * 256 + threadIdx.x;
        if (e >= kET) return;
        int src, dst;
        edge_pair(ei, e, src, dst);
        int pos = atomicAdd(&cursor[dst], 1);
        src_csr[pos] = src;
    }
}

// Fused edge-softmax + aggregation. One wave per dst.
__global__ void __launch_bounds__(256) k_gat(const int* __restrict__ rowptr,
                                             const int* __restrict__ srcc,
                                             const float* __restrict__ es,
                                             const float* __restrict__ ed,
                                             const ushort* __restrict__ h,
                                             ushort* __restrict__ z) {
    int wid = threadIdx.x >> 6;
    int lane = threadIdx.x & 63;
    int dst = blockIdx.x * 4 + wid;   // kN % 4 == 0
    int start = rowptr[dst], end = rowptr[dst + 1];
    int deg = end - start;

    int e_l = lane >> 2, hh = lane & 3;    // score mapping
    int q = lane >> 4, c4 = lane & 15;     // gather mapping

    float edv = ed[dst * 4 + hh];
    float acc[4][4] = {};
    float s;

    if (deg <= 16) {
        int pos = start + e_l;
        int psafe = (pos < end) ? pos : start;
        int src = srcc[psafe];
        float v = es[src * 4 + hh] + edv;
        v = (v >= 0.f) ? v : 0.2f * v;
        if (pos >= end) v = -3e38f;

        uint2 hv[4];
#pragma unroll
        for (int t = 0; t < 4; ++t) {
            int p2 = start + t * 4 + q;
            int p2s = (p2 < end) ? p2 : start;
            int s2 = srcc[p2s];
            hv[t] = *reinterpret_cast<const uint2*>(h + (size_t)s2 * 64 + c4 * 4);
        }

        float cm = v;
        cm = fmaxf(cm, __shfl_xor(cm, 4));
        cm = fmaxf(cm, __shfl_xor(cm, 8));
        cm = fmaxf(cm, __shfl_xor(cm, 16));
        cm = fmaxf(cm, __shfl_xor(cm, 32));
        float p = __expf(v - cm);
        float cs = p;
        cs += __shfl_xor(cs, 4);
        cs += __shfl_xor(cs, 8);
        cs += __shfl_xor(cs, 16);
        cs += __shfl_xor(cs, 32);
        s = cs;

#pragma unroll
        for (int t = 0; t < 4; ++t) {
            int el = t * 4 + q;
            float p0 = __shfl(p, (el << 2) | 0);
            float p1 = __shfl(p, (el << 2) | 1);
            float p2 = __shfl(p, (el << 2) | 2);
            float p3 = __shfl(p, (el << 2) | 3);
            float c0 = __uint_as_float(hv[t].x << 16);
            float c1 = __uint_as_float(hv[t].x & 0xFFFF0000u);
            float c2 = __uint_as_float(hv[t].y << 16);
            float c3 = __uint_as_float(hv[t].y & 0xFFFF0000u);
            acc[0][0] += p0 * c0; acc[0][1] += p0 * c1; acc[0][2] += p0 * c2; acc[0][3] += p0 * c3;
            acc[1][0] += p1 * c0; acc[1][1] += p1 * c1; acc[1][2] += p1 * c2; acc[1][3] += p1 * c3;
            acc[2][0] += p2 * c0; acc[2][1] += p2 * c1; acc[2][2] += p2 * c2; acc[2][3] += p2 * c3;
            acc[3][0] += p3 * c0; acc[3][1] += p3 * c1; acc[3][2] += p3 * c2; acc[3][3] += p3 * c3;
        }
    } else {
        float m = -3e38f;
        s = 0.f;
        for (int cs0 = start; cs0 < end; cs0 += 16) {
            int pos = cs0 + e_l;
            int psafe = (pos < end) ? pos : start;
            int src = srcc[psafe];
            float v = es[src * 4 + hh] + edv;
            v = (v >= 0.f) ? v : 0.2f * v;
            if (pos >= end) v = -3e38f;

            float cm = v;
            cm = fmaxf(cm, __shfl_xor(cm, 4));
            cm = fmaxf(cm, __shfl_xor(cm, 8));
            cm = fmaxf(cm, __shfl_xor(cm, 16));
            cm = fmaxf(cm, __shfl_xor(cm, 32));
            float mn = fmaxf(m, cm);
            float scale = __expf(m - mn);
            float p = __expf(v - mn);
            float cth = p;
            cth += __shfl_xor(cth, 4);
            cth += __shfl_xor(cth, 8);
            cth += __shfl_xor(cth, 16);
            cth += __shfl_xor(cth, 32);
            s = s * scale + cth;
            m = mn;

            float sc0 = __shfl(scale, 0), sc1 = __shfl(scale, 1);
            float sc2 = __shfl(scale, 2), sc3 = __shfl(scale, 3);
#pragma unroll
            for (int c = 0; c < 4; ++c) {
                acc[0][c] *= sc0; acc[1][c] *= sc1; acc[2][c] *= sc2; acc[3][c] *= sc3;
            }
#pragma unroll
            for (int t = 0; t < 4; ++t) {
                int el = t * 4 + q;
                int p2 = cs0 + el;
                int p2s = (p2 < end) ? p2 : start;
                int s2 = srcc[p2s];
                uint2 hv = *reinterpret_cast<const uint2*>(h + (size_t)s2 * 64 + c4 * 4);
                float p0 = __shfl(p, (el << 2) | 0);
                float p1 = __shfl(p, (el << 2) | 1);
                float p2f = __shfl(p, (el << 2) | 2);
                float p3 = __shfl(p, (el << 2) | 3);
                float c0 = __uint_as_float(hv.x << 16);
                float c1 = __uint_as_float(hv.x & 0xFFFF0000u);
                float c2 = __uint_as_float(hv.y << 16);
                float c3 = __uint_as_float(hv.y & 0xFFFF0000u);
                acc[0][0] += p0 * c0;  acc[0][1] += p0 * c1;  acc[0][2] += p0 * c2;  acc[0][3] += p0 * c3;
                acc[1][0] += p1 * c0;  acc[1][1] += p1 * c1;  acc[1][2] += p1 * c2;  acc[1][3] += p1 * c3;
                acc[2][0] += p2f * c0; acc[2][1] += p2f * c1; acc[2][2] += p2f * c2; acc[2][3] += p2f * c3;
                acc[3][0] += p3 * c0;  acc[3][1] += p3 * c1;  acc[3][2] += p3 * c2;  acc[3][3] += p3 * c3;
            }
        }
    }

    float myinv = 0.25f / (s + 1e-16f);
    float inv0 = __shfl(myinv, 0), inv1 = __shfl(myinv, 1);
    float inv2 = __shfl(myinv, 2), inv3 = __shfl(myinv, 3);
#pragma unroll
    for (int c = 0; c < 4; ++c) {
        acc[0][c] *= inv0; acc[1][c] *= inv1; acc[2][c] *= inv2; acc[3][c] *= inv3;
    }
#pragma unroll
    for (int j = 0; j < 4; ++j) {
#pragma unroll
        for (int c = 0; c < 4; ++c) {
            float v = acc[j][c];
            v += __shfl_xor(v, 16);
            v += __shfl_xor(v, 32);
            acc[j][c] = v;
        }
    }
    if (q == 0) {
        ushort* zr = z + (size_t)dst * 256 + c4 * 4;
#pragma unroll
        for (int j = 0; j < 4; ++j) {
            ushort4 o;
            o.x = f2b(acc[j][0]); o.y = f2b(acc[j][1]);
            o.z = f2b(acc[j][2]); o.w = f2b(acc[j][3]);
            *reinterpret_cast<ushort4*>(zr + j * 64) = o;
        }
    }
}

// MFMA GEMM: one wave = one 16x16 output tile (8 MFMAs). Fused BN stats ->
// LDS combine -> 2*DOUT atomicAdds into replica row (blockIdx & (kRep-1)).
template <int DOUT>
__global__ void __launch_bounds__(256) k_zgemm(const ushort* __restrict__ z,
                                               const ushort* __restrict__ Wt2l,
                                               float* __restrict__ hnext,
                                               float* __restrict__ bnrep_l) {
    constexpr int NT = DOUT / 16;
    constexpr int W = 2 * DOUT;
    __shared__ float pl[4][W];
    int tid = threadIdx.x;
    int widx = tid >> 6, lane = tid & 63;
    int wid = blockIdx.x * 4 + widx;
    int mtile = wid / NT;
    int nt = wid - mtile * NT;
    bool active = (mtile < kN / 16);
    int m0 = mtile * 16;
    int n0 = nt * 16;

    int row = lane & 15;
    int k0  = (lane >> 4) * 8;

    // zero-init LDS partials
    for (int j = tid; j < 4 * W; j += 256) (&pl[0][0])[j] = 0.f;

    f32x4 acc = {0.f, 0.f, 0.f, 0.f};
    if (active) {
        const ushort* za = z + (size_t)(m0 + row) * 256 + k0;
        const ushort* wb = Wt2l + (size_t)(n0 + row) * 256 + k0;
#pragma unroll
        for (int ks = 0; ks < 8; ++ks) {
            bf16x8 a = *reinterpret_cast<const bf16x8*>(za + ks * 32);
            bf16x8 b = *reinterpret_cast<const bf16x8*>(wb + ks * 32);
            acc = __builtin_amdgcn_mfma_f32_16x16x32_bf16(a, b, acc, 0, 0, 0);
        }
        int col = lane & 15;
        int r0  = (lane >> 4) * 4;
#pragma unroll
        for (int r = 0; r < 4; ++r)
            hnext[(size_t)(m0 + r0 + r) * DOUT + n0 + col] = acc[r];
    }

    // per-wave column stats (zeros if inactive)
    float s0 = 0.f, q0 = 0.f;
#pragma unroll
    for (int r = 0; r < 4; ++r) { s0 += acc[r]; q0 += acc[r] * acc[r]; }
    s0 += __shfl_xor(s0, 16); s0 += __shfl_xor(s0, 32);
    q0 += __shfl_xor(q0, 16); q0 += __shfl_xor(q0, 32);
    __syncthreads();   // init complete before per-wave writes
    if (lane < 16) {
        pl[widx][n0 + lane]        = s0;
        pl[widx][DOUT + n0 + lane] = q0;
    }
    __syncthreads();
    if (tid < W) {
        float t = pl[0][tid] + pl[1][tid] + pl[2][tid] + pl[3][tid];
        atomicAdd(&bnrep_l[(blockIdx.x & (kRep - 1)) * 128 + tid], t);
    }
}

// BN apply (layers 0,1) fused with NEXT layer's es/ed; sums kRep BN replicas.
__global__ void __launch_bounds__(256) k_bn_apply_att(const float* __restrict__ hnext,
                                                      const float* __restrict__ bnrep_l,
                                                      const float* __restrict__ g,
                                                      const float* __restrict__ be,
                                                      const float* __restrict__ ahat_next,
                                                      ushort* __restrict__ hcur,
                                                      float* __restrict__ es,
                                                      float* __restrict__ ed) {
    int node = blockIdx.x * 4 + (threadIdx.x >> 6);
    int lane = threadIdx.x & 63;
    float bs = 0.f, bq = 0.f;
#pragma unroll
    for (int r = 0; r < kRep; ++r) {
        bs += bnrep_l[r * 128 + lane];
        bq += bnrep_l[r * 128 + 64 + lane];
    }
    float mu = bs * (1.f / kN);
    float var = bq * (1.f / kN) - mu * mu;
    float v = g[lane] * (hnext[(size_t)node * 64 + lane] - mu) * rsqrtf(var + 1e-5f) + be[lane];
    v = fmaxf(v, 0.f);
    hcur[(size_t)node * 64 + lane] = f2b(v);

    float ps[4], pd[4];
#pragma unroll
    for (int hh = 0; hh < 4; ++hh) {
        ps[hh] = v * ahat_next[hh * 64 + lane];
        pd[hh] = v * ahat_next[256 + hh * 64 + lane];
    }
#pragma unroll
    for (int off = 1; off < 64; off <<= 1) {
#pragma unroll
        for (int hh = 0; hh < 4; ++hh) {
            ps[hh] += __shfl_xor(ps[hh], off);
            pd[hh] += __shfl_xor(pd[hh], off);
        }
    }
    if (lane == 0) {
        ((float4*)es)[node] = make_float4(ps[0], ps[1], ps[2], ps[3]);
        ((float4*)ed)[node] = make_float4(pd[0], pd[1], pd[2], pd[3]);
    }
}

// final BN apply (layer 2) fused with pooling partials; sums kRep BN replicas.
__global__ void __launch_bounds__(256) k_bn_apply32_pool(const float* __restrict__ hnext,
                                                         const float* __restrict__ bnrep_l,
                                                         const float* __restrict__ g,
                                                         const float* __restrict__ be,
                                                         const int* __restrict__ batch,
                                                         float* __restrict__ out_h,
                                                         float* __restrict__ gsum,
                                                         unsigned* __restrict__ gmaxe) {
    int tid = threadIdx.x;
    int i = blockIdx.x * 256 + tid;   // exactly kN*32 threads
    int n = i >> 5, c = i & 31;
    float bs = 0.f, bq = 0.f;
#pragma unroll
    for (int r = 0; r < kRep; ++r) {
        bs += bnrep_l[r * 128 + c];
        bq += bnrep_l[r * 128 + 32 + c];
    }
    float mu = bs * (1.f / kN);
    float var = bq * (1.f / kN) - mu * mu;
    float v = g[c] * (hnext[i] - mu) * rsqrtf(var + 1e-5f) + be[c];
    out_h[i] = v;

    __shared__ float ls[256];
    ls[tid] = v;
    __syncthreads();
    int nb0 = blockIdx.x * 8;
    int gfirst = batch[nb0], glast = batch[nb0 + 7];
    if (gfirst == glast) {
        if (tid < 32) {
            float s = 0.f;
            unsigned me = 0u;
#pragma unroll
            for (int r = 0; r < 8; ++r) {
                float vv = ls[r * 32 + tid];
                s += vv;
                unsigned e = enc_f(vv);
                me = (e > me) ? e : me;
            }
            atomicAdd(&gsum[gfirst * 32 + tid], s);
            atomicMax(&gmaxe[gfirst * 32 + tid], me);
        }
    } else {
        int gg = batch[n];
        atomicAdd(&gsum[gg * 32 + c], v);
        atomicMax(&gmaxe[gg * 32 + c], enc_f(v));
    }
}

// finalize pooling + both MLP heads (single block)
__global__ void __launch_bounds__(256) k_finish(const float* __restrict__ gsum,
                                                const unsigned* __restrict__ gmaxe,
                                                const int* __restrict__ batch,
                                                const float* __restrict__ ew1,
                                                const float* __restrict__ eb1,
                                                const float* __restrict__ ew2,
                                                const float* __restrict__ eb2,
                                                const float* __restrict__ mw1,
                                                const float* __restrict__ mb1,
                                                const float* __restrict__ mw2,
                                                const float* __restrict__ mb2,
                                                float* __restrict__ out_gemb,
                                                float* __restrict__ out_eth,
                                                float* __restrict__ out_man) {
    __shared__ int bound[kG + 1];
    __shared__ float ge[kG * 32];
    int tid = threadIdx.x;
    if (tid <= kG) {
        int lo = 0, hi = kN;
        while (lo < hi) { int mid = (lo + hi) >> 1; if (batch[mid] < tid) lo = mid + 1; else hi = mid; }
        bound[tid] = lo;
    }
    __syncthreads();
    for (int j = tid; j < kG * 32; j += 256) {
        int gg = j >> 5;
        int cnt = bound[gg + 1] - bound[gg];
        float sum = gsum[j];
        float mx = (cnt > 0) ? dec_f(gmaxe[j]) : 0.f;
        float mean = sum / fmaxf((float)cnt, 1.f);
        float e = (mean + mx + sum) * (1.f / 3.f);
        ge[j] = e;
        out_gemb[j] = e;
    }
    __syncthreads();
    if (tid < kG) {
        const float* row = &ge[tid * 32];
        float acc_e = eb2[0], acc_m = mb2[0];
#pragma unroll 4
        for (int j = 0; j < 16; ++j) {
            float he = eb1[j], hm = mb1[j];
            for (int k = 0; k < 32; ++k) {
                float v = row[k];
                he += v * ew1[k * 16 + j];
                hm += v * mw1[k * 16 + j];
            }
            acc_e += fmaxf(he, 0.f) * ew2[j];
            acc_m += fmaxf(hm, 0.f) * mw2[j];
        }
        out_eth[tid] = 1.f / (1.f + expf(-acc_e));
        out_man[tid] = 1.f / (1.f + expf(-acc_m));
    }
}

extern "C" void kernel_launch(void* const* d_in, const int* in_sizes, int n_in,
                              void* d_out, int out_size, void* d_ws, size_t ws_size,
                              hipStream_t stream) {
    const float* x     = (const float*)d_in[0];
    const int*   ei    = (const int*)d_in[1];
    const int*   batch = (const int*)d_in[2];
    const float* enc_w = (const float*)d_in[3];
    const float* enc_b = (const float*)d_in[4];

    float* ws = (float*)d_ws;
    ushort*   hcur  = (ushort*)(ws + OFF_HCUR);
    float*    hnext = ws + OFF_HNEXT;
    ushort*   z     = (ushort*)(ws + OFF_Z);
    float*    es    = ws + OFF_ES;
    float*    ed    = ws + OFF_ED;
    int*      rowptr= (int*)(ws + OFF_ROWPTR);
    int*      srcc  = (int*)(ws + OFF_SRC);
    ushort*   Wt2   = (ushort*)(ws + OFF_WT2);
    float*    ahat  = ws + OFF_AHAT;
    int*      spart = (int*)(ws + OFF_SPART);
    int*      cursor= (int*)(ws + OFF_CURSOR);
    float*    bnrep = ws + OFF_BNREP;
    float*    gsum  = ws + OFF_GPOOL;
    unsigned* gmaxe = (unsigned*)(ws + OFF_GPOOL + 1600);

    float* out      = (float*)d_out;
    float* out_h    = out;                 // N*32
    float* out_gemb = out + 1600000;       // G*32
    float* out_eth  = out + 1601600;       // G
    float* out_man  = out + 1601650;       // G

    // ---- single zero-init: cursor + bnrep + gpool (contiguous) ----
    hipMemsetAsync(ws + OFF_CURSOR, 0, (kZeroEnd - OFF_CURSOR) * sizeof(float), stream);

    // ---- weight prep + dst histogram (fused) ----
    k_histprep<<<kPrepBlocks + kHistBlocks, 256, 0, stream>>>(
        ei, cursor,
        (const float*)d_in[5], (const float*)d_in[11], (const float*)d_in[17],
        (const float*)d_in[6], (const float*)d_in[12], (const float*)d_in[18],
        (const float*)d_in[7], (const float*)d_in[13], (const float*)d_in[19],
        ahat, Wt2);

    // ---- scan ----
    k_scan_local<<<kScanBlocks, 1024, 0, stream>>>(cursor, rowptr, spart);
    k_scan_part<<<1, 64, 0, stream>>>(spart);
    k_scan_add<<<kScanBlocks, 1024, 0, stream>>>(cursor, rowptr, spart);

    // ---- scatter + encoder/layer-0 att (fused) ----
    k_scatter_enc<<<kEncBlocks + kHistBlocks, 256, 0, stream>>>(
        ei, cursor, srcc, x, enc_w, enc_b, ahat, hcur, es, ed);

    for (int l = 0; l < 3; ++l) {
        const float* gam = (const float*)d_in[9 + 6 * l];
        const float* bet = (const float*)d_in[10 + 6 * l];
        const ushort* Wt2l = Wt2 + l * 16384;
        float* bnrep_l = bnrep + l * kRep * 128;

        k_gat<<<kN / 4, 256, 0, stream>>>(rowptr, srcc, es, ed, hcur, z);

        if (l < 2) {
            k_zgemm<64><<<3125, 256, 0, stream>>>(z, Wt2l, hnext, bnrep_l);
            k_bn_apply_att<<<kN / 4, 256, 0, stream>>>(hnext, bnrep_l, gam, bet,
                                                       ahat + (l + 1) * 512, hcur, es, ed);
        } else {
            k_zgemm<32><<<1563, 256, 0, stream>>>(z, Wt2l, hnext, bnrep_l);
            k_bn_apply32_pool<<<kN * 32 / 256, 256, 0, stream>>>(hnext, bnrep_l, gam, bet,
                                                                 batch, out_h, gsum, gmaxe);
        }
    }

    k_finish<<<1, 256, 0, stream>>>(gsum, gmaxe, batch,
                                    (const float*)d_in[23], (const float*)d_in[24],
                                    (const float*)d_in[25], (const float*)d_in[26],
                                    (const float*)d_in[27], (const float*)d_in[28],
                                    (const float*)d_in[29], (const float*)d_in[30],
                                    out_gemb, out_eth, out_man);
}